// Round 9
// baseline (179.732 us; speedup 1.0000x reference)
//
#include <hip/hip_runtime.h>
#include <hip/hip_bf16.h>

#define DIM 768
#define NTOK 32768
#define TTOK 16
#define NBLK 128
#define GRID_MAIN 512
#define PSZ 256
#define XPITCH 264

typedef __attribute__((ext_vector_type(8))) short short8;
typedef __attribute__((ext_vector_type(4))) float f32x4;

__device__ __forceinline__ unsigned short f2bf(float f) {
  union { float f; unsigned int u; } v; v.f = f;
  unsigned int u = v.u;
  return (unsigned short)((u + 0x7fffu + ((u >> 16) & 1u)) >> 16);
}

// ---- pass 1: per-(block,expert) histogram
__global__ void hist_kernel(const int* __restrict__ mask, int* __restrict__ hist) {
  int tid = threadIdx.x, b = blockIdx.x;
  int gid = b * 256 + tid;
  int wv = tid >> 6, lane = tid & 63;
  int e = mask[gid] & 3;
  __shared__ int wcnt[4][4];
  #pragma unroll
  for (int q = 0; q < 4; ++q) {
    unsigned long long m = __ballot(e == q);
    if (lane == 0) wcnt[wv][q] = __popcll(m);
  }
  __syncthreads();
  if (tid < 4)
    hist[tid * NBLK + b] = wcnt[0][tid] + wcnt[1][tid] + wcnt[2][tid] + wcnt[3][tid];
}

// ---- pass 2: single-wave exclusive scan over 512 (expert-major) entries
__global__ void scan_kernel(const int* __restrict__ hist, int* __restrict__ base,
                            int* __restrict__ meta) {
  int lane = threadIdx.x;  // 64 threads
  int v[8];
  int lsum = 0;
  #pragma unroll
  for (int j = 0; j < 8; ++j) {
    int t = hist[lane * 8 + j];
    v[j] = lsum; lsum += t;
  }
  int inc = lsum;
  #pragma unroll
  for (int d = 1; d < 64; d <<= 1) {
    int u = __shfl_up(inc, d);
    if (lane >= d) inc += u;
  }
  int excl = inc - lsum;
  #pragma unroll
  for (int j = 0; j < 8; ++j) base[lane * 8 + j] = excl + v[j];
  __syncthreads();
  if (lane == 0) {
    int est[5];
    #pragma unroll
    for (int e = 0; e < 4; ++e) est[e] = base[e * NBLK];
    est[4] = NTOK;
    int s = 0;
    #pragma unroll
    for (int e = 0; e < 5; ++e) meta[e] = est[e];
    #pragma unroll
    for (int e = 0; e < 4; ++e) {
      meta[8 + e] = s;
      s += (est[e + 1] - est[e] + TTOK - 1) / TTOK;
    }
    meta[12] = s;
  }
}

// ---- pass 3: scatter tokens to exact sorted positions
__global__ void scatter_kernel(const int* __restrict__ mask, const int* __restrict__ base,
                               int* __restrict__ lists) {
  int tid = threadIdx.x, b = blockIdx.x;
  int gid = b * 256 + tid;
  int wv = tid >> 6, lane = tid & 63;
  int e = mask[gid] & 3;
  __shared__ int wcnt[4][4];
  __shared__ int wbase[4][4];
  unsigned long long lt = (1ull << lane) - 1ull;
  int rank = 0;
  #pragma unroll
  for (int q = 0; q < 4; ++q) {
    unsigned long long m = __ballot(e == q);
    if (e == q) rank = __popcll(m & lt);
    if (lane == 0) wcnt[wv][q] = __popcll(m);
  }
  __syncthreads();
  if (tid < 4) {
    int s = 0;
    #pragma unroll
    for (int w2 = 0; w2 < 4; ++w2) { int c = wcnt[w2][tid]; wbase[w2][tid] = s; s += c; }
  }
  __syncthreads();
  lists[base[e * NBLK + b] + wbase[wv][e] + rank] = gid;
}

// ---- weight repack to bf16 (WdT [ds][768], WuT [768][KP] zero-padded)
__global__ void prep_kernel(const float* __restrict__ Wd0, const float* __restrict__ Wd1,
                            const float* __restrict__ Wd2, const float* __restrict__ Wd3,
                            const float* __restrict__ Wu0, const float* __restrict__ Wu1,
                            const float* __restrict__ Wu2, const float* __restrict__ Wu3,
                            unsigned short* __restrict__ wdT, unsigned short* __restrict__ wuT) {
  int e = blockIdx.x;
  int ds = 16 << e;
  int lgK = (e == 0) ? 5 : (4 + e);
  int KP = 1 << lgK;
  const float* Wd = (e == 0) ? Wd0 : (e == 1) ? Wd1 : (e == 2) ? Wd2 : Wd3;
  const float* Wu = (e == 0) ? Wu0 : (e == 1) ? Wu1 : (e == 2) ? Wu2 : Wu3;
  const int WOFF[4] = {0, 12288, 36864, 86016};
  const int UOFF[4] = {0, 24576, 49152, 98304};
  int stride = gridDim.y * 256;
  int start = blockIdx.y * 256 + threadIdx.x;
  int nd = ds * DIM;
  for (int i = start; i < nd; i += stride) {
    int k = i / DIM, d = i - k * DIM;
    wdT[WOFF[e] + i] = f2bf(Wd[d * ds + k]);
  }
  int nu = DIM << lgK;
  for (int i = start; i < nu; i += stride) {
    int dc = i >> lgK, k = i & (KP - 1);
    wuT[UOFF[e] + i] = (k < ds) ? f2bf(Wu[k * DIM + dc]) : (unsigned short)0;
  }
}

__device__ __forceinline__ int expert_of(int w, const int* __restrict__ ts) {
  return (w >= ts[2]) ? ((w >= ts[3]) ? 3 : 2) : ((w >= ts[1]) ? 1 : 0);
}

// issue one 256-float panel of this wave's 4 rows into registers (no wait)
__device__ __forceinline__ void issue_panel(const int tk[4], int p, int lane,
                                            const float* __restrict__ x, float4 v[4]) {
  int c = p * PSZ + lane * 4;
  #pragma unroll
  for (int i = 0; i < 4; ++i) {
    int t = tk[i];
    float4 vv = {0.f, 0.f, 0.f, 0.f};
    if (t >= 0) vv = *(const float4*)(x + (size_t)t * DIM + c);
    v[i] = vv;
  }
}

__device__ __forceinline__ void write_panel(int wv, int lane, const float4 v[4],
                                            unsigned short* __restrict__ buf) {
  #pragma unroll
  for (int i = 0; i < 4; ++i) {
    int r = wv * 4 + i;
    ushort4 b;
    b.x = f2bf(v[i].x); b.y = f2bf(v[i].y); b.z = f2bf(v[i].z); b.w = f2bf(v[i].w);
    *(ushort4*)(buf + r * XPITCH + lane * 4) = b;
  }
}

// ---- one 16-token tile: 3 k-panels double-buffered; next-tile P0 issued
// mid-tile so HBM reads are in flight during every phase.
template <int E>
__device__ __forceinline__ void moe_tile(
    int wv, int lane, int tid,
    const float* __restrict__ x,
    const unsigned short* __restrict__ wdT, const unsigned short* __restrict__ wuT,
    const float* __restrict__ bd, const float* __restrict__ bu,
    float* __restrict__ out,
    const int* __restrict__ listsE, int base, int cnt,
    float4 (&cv)[4], const int tkc[4], const int tkn[4],
    unsigned short* __restrict__ xp, float* __restrict__ dnpart,
    unsigned short (*dn)[136]) {
  constexpr int DS = 16 << E;
  constexpr int KP = (E == 0) ? 32 : DS;
  constexpr int NTA = DS / 16;
  constexpr int SPLIT_N = (NTA < 4) ? NTA : 4;   // 1,2,4,4
  constexpr int SPLIT_K = 4 / SPLIT_N;           // 4,2,1,1
  constexpr int NTB = NTA / SPLIT_N;             // 1,1,1,2
  constexpr int KB = KP / 32;                    // 1,1,2,4
  constexpr int WOFF[4] = {0, 12288, 36864, 86016};
  constexpr int UOFF[4] = {0, 24576, 49152, 98304};
  const unsigned short* wd = wdT + WOFF[E];
  const unsigned short* wu = wuT + UOFF[E];
  unsigned short* xp0 = xp;
  unsigned short* xp1 = xp + TTOK * XPITCH;

  int lrow = lane & 15, kg = lane >> 4;
  int nsub = wv % SPLIT_N, ksub = wv / SPLIT_N;

  // epilogue token ids (rows kg*4+r) — direct loads, L2-hot
  int tke[4];
  #pragma unroll
  for (int r = 0; r < 4; ++r) {
    int rr = kg * 4 + r;
    tke[r] = (base + rr < cnt) ? listsE[base + rr] : -1;
  }

  if (SPLIT_K > 1) {
    for (int i = tid; i < TTOK * DS; i += 256) dnpart[i] = 0.f;
  }

  f32x4 acc[NTB];
  #pragma unroll
  for (int nb = 0; nb < NTB; ++nb) acc[nb] = f32x4{0.f, 0.f, 0.f, 0.f};

  const unsigned short* wdbase = wd + (size_t)(nsub * NTB * 16 + lrow) * DIM + kg * 8;

  // ---- pipelined panels: write P0, issue P1 | mfma P0, write P1, issue P2 |
  //      mfma P1, write P2, issue next-tile P0 | mfma P2
  write_panel(wv, lane, cv, xp0);
  float4 r1[4];
  issue_panel(tkc, 1, lane, x, r1);
  __syncthreads();

  #pragma unroll
  for (int p = 0; p < 3; ++p) {
    const unsigned short* bufc = (p & 1) ? xp1 : xp0;
    bool mine = (SPLIT_K == 1) ? true
               : (SPLIT_K == 2) ? ((p & 1) == ksub)
               : (wv == p);
    if (mine) {
      const unsigned short* xr = bufc + lrow * XPITCH + kg * 8;
      const unsigned short* wr = wdbase + p * PSZ;
      #pragma unroll
      for (int ks = 0; ks < 8; ++ks) {
        short8 a = *(const short8*)(xr + ks * 32);
        #pragma unroll
        for (int nb = 0; nb < NTB; ++nb) {
          short8 b = *(const short8*)(wr + (size_t)nb * 16 * DIM + ks * 32);
          acc[nb] = __builtin_amdgcn_mfma_f32_16x16x32_bf16(a, b, acc[nb], 0, 0, 0);
        }
      }
    }
    if (p == 0) {
      write_panel(wv, lane, r1, xp1);
      float4 r2[4];
      issue_panel(tkc, 2, lane, x, r2);
      #pragma unroll
      for (int i = 0; i < 4; ++i) r1[i] = r2[i];
      __syncthreads();
    } else if (p == 1) {
      write_panel(wv, lane, r1, xp0);
      issue_panel(tkn, 0, lane, x, cv);   // next tile's P0 — in flight through B
      __syncthreads();
    }
  }

  // ---- dn production
  if (SPLIT_K > 1) {
    if (SPLIT_K != 4 || wv < 3) {
      int kc = nsub * 16 + lrow;
      #pragma unroll
      for (int r = 0; r < 4; ++r)
        atomicAdd(&dnpart[(kg * 4 + r) * DS + kc], acc[0][r]);
    }
    __syncthreads();
    for (int i = tid; i < TTOK * KP; i += 256) {
      int tt = i / KP, k = i - tt * KP;
      float v = (k < DS) ? fmaxf(dnpart[tt * DS + k] + bd[k], 0.f) : 0.f;
      dn[tt][k] = f2bf(v);
    }
  } else {
    #pragma unroll
    for (int nb = 0; nb < NTB; ++nb) {
      int kc = (nsub * NTB + nb) * 16 + lrow;
      float bv = bd[kc];
      #pragma unroll
      for (int r = 0; r < 4; ++r)
        dn[kg * 4 + r][kc] = f2bf(fmaxf(acc[nb][r] + bv, 0.f));
    }
  }
  __syncthreads();

  // ---- phase B: wave owns dcols [192*wv, 192*wv+192); direct stores +
  // batched residual reads (L2/L3-hot)
  short8 afr[KB];
  #pragma unroll
  for (int k = 0; k < KB; ++k) afr[k] = *(const short8*)&dn[lrow][k * 32 + kg * 8];
  const unsigned short* wurow = wu + (size_t)(wv * 192 + lrow) * KP + kg * 8;

  #pragma unroll 4
  for (int nn = 0; nn < 12; ++nn) {
    f32x4 c = {0.f, 0.f, 0.f, 0.f};
    #pragma unroll
    for (int k = 0; k < KB; ++k) {
      short8 b = *(const short8*)(wurow + (size_t)nn * 16 * KP + k * 32);
      c = __builtin_amdgcn_mfma_f32_16x16x32_bf16(afr[k], b, c, 0, 0, 0);
    }
    int dcol = (wv * 12 + nn) * 16 + lrow;
    float bv = bu[dcol];
    #pragma unroll
    for (int r = 0; r < 4; ++r) {
      int tt = tke[r];
      if (tt >= 0) {
        size_t o = (size_t)tt * DIM + dcol;
        out[o] = c[r] + bv + x[o];
      }
    }
  }
}

__global__ __launch_bounds__(256, 4) void moe_main(
    const float* __restrict__ x,
    const int* __restrict__ meta, const int* __restrict__ lists,
    const unsigned short* __restrict__ wdT, const unsigned short* __restrict__ wuT,
    const float* __restrict__ bd0, const float* __restrict__ bd1,
    const float* __restrict__ bd2, const float* __restrict__ bd3,
    const float* __restrict__ bu0, const float* __restrict__ bu1,
    const float* __restrict__ bu2, const float* __restrict__ bu3,
    float* __restrict__ out) {
  __shared__ unsigned short xp[2 * TTOK * XPITCH];
  __shared__ float dnpart[TTOK * 32];
  __shared__ unsigned short dn[TTOK][136];
  int tid = threadIdx.x, wv = tid >> 6, lane = tid & 63;
  const int* ts = meta + 8;
  int ntiles = ts[4];
  int w = blockIdx.x;
  if (w >= ntiles) return;

  // prologue: ids + issue P0 of first tile
  int tkc[4];
  {
    int e = expert_of(w, ts);
    int base = (w - ts[e]) * TTOK;
    int cnt = meta[e + 1] - meta[e];
    const int* listsE = lists + meta[e];
    #pragma unroll
    for (int i = 0; i < 4; ++i) {
      int r = base + wv * 4 + i;
      tkc[i] = (r < cnt) ? listsE[r] : -1;
    }
  }
  float4 cv[4];
  issue_panel(tkc, 0, lane, x, cv);

  for (; w < ntiles; w += GRID_MAIN) {
    int e = expert_of(w, ts);
    int base = (w - ts[e]) * TTOK;
    int cnt = meta[e + 1] - meta[e];
    const int* listsE = lists + meta[e];

    int wn = w + GRID_MAIN;
    int tkn[4];
    if (wn < ntiles) {
      int en = expert_of(wn, ts);
      int basen = (wn - ts[en]) * TTOK;
      int cntn = meta[en + 1] - meta[en];
      const int* listsEn = lists + meta[en];
      #pragma unroll
      for (int i = 0; i < 4; ++i) {
        int r = basen + wv * 4 + i;
        tkn[i] = (r < cntn) ? listsEn[r] : -1;
      }
    } else {
      #pragma unroll
      for (int i = 0; i < 4; ++i) tkn[i] = -1;
    }

    if (e == 0)
      moe_tile<0>(wv, lane, tid, x, wdT, wuT, bd0, bu0, out, listsE, base, cnt,
                  cv, tkc, tkn, xp, dnpart, dn);
    else if (e == 1)
      moe_tile<1>(wv, lane, tid, x, wdT, wuT, bd1, bu1, out, listsE, base, cnt,
                  cv, tkc, tkn, xp, dnpart, dn);
    else if (e == 2)
      moe_tile<2>(wv, lane, tid, x, wdT, wuT, bd2, bu2, out, listsE, base, cnt,
                  cv, tkc, tkn, xp, dnpart, dn);
    else
      moe_tile<3>(wv, lane, tid, x, wdT, wuT, bd3, bu3, out, listsE, base, cnt,
                  cv, tkc, tkn, xp, dnpart, dn);

    #pragma unroll
    for (int i = 0; i < 4; ++i) tkc[i] = tkn[i];
  }
}

extern "C" void kernel_launch(void* const* d_in, const int* in_sizes, int n_in,
                              void* d_out, int out_size, void* d_ws, size_t ws_size,
                              hipStream_t stream) {
  const float* x = (const float*)d_in[0];
  const int* mask = (const int*)d_in[1];
  const float* Wd[4]; const float* bd[4]; const float* Wu[4]; const float* bu[4];
  for (int i = 0; i < 4; ++i) {
    Wd[i] = (const float*)d_in[2 + 4 * i];
    bd[i] = (const float*)d_in[3 + 4 * i];
    Wu[i] = (const float*)d_in[4 + 4 * i];
    bu[i] = (const float*)d_in[5 + 4 * i];
  }
  char* ws = (char*)d_ws;
  int* hist = (int*)ws;                                  // 2048 B
  int* base = (int*)(ws + 2048);                         // 2048 B
  int* meta = (int*)(ws + 4096);                         // 64 B
  int* lists = (int*)(ws + 4352);                        // 131072 B (sorted, concatenated)
  unsigned short* wdT = (unsigned short*)(ws + 135424);  // 368640 B
  unsigned short* wuT = (unsigned short*)(ws + 504064);  // 393216 B

  hist_kernel<<<NBLK, 256, 0, stream>>>(mask, hist);
  scan_kernel<<<1, 64, 0, stream>>>(hist, base, meta);
  scatter_kernel<<<NBLK, 256, 0, stream>>>(mask, base, lists);
  prep_kernel<<<dim3(4, 32), 256, 0, stream>>>(Wd[0], Wd[1], Wd[2], Wd[3],
                                               Wu[0], Wu[1], Wu[2], Wu[3], wdT, wuT);
  moe_main<<<GRID_MAIN, 256, 0, stream>>>(x, meta, lists, wdT, wuT,
                                          bd[0], bd[1], bd[2], bd[3],
                                          bu[0], bu[1], bu[2], bu[3],
                                          (float*)d_out);
}